// Round 1
// baseline (322.709 us; speedup 1.0000x reference)
//
#include <hip/hip_runtime.h>

typedef short shortx8 __attribute__((ext_vector_type(8)));
typedef float floatx4 __attribute__((ext_vector_type(4)));
typedef unsigned short ushortx4 __attribute__((ext_vector_type(4)));

typedef __attribute__((address_space(1))) char gchar;
typedef __attribute__((address_space(3))) char lchar;

__device__ __forceinline__ void async16(const void* g, void* l) {
    __builtin_amdgcn_global_load_lds((gchar*)g, (lchar*)l, 16, 0, 0);
}

__device__ __forceinline__ unsigned short f2bf(float f) {
    union { float f; unsigned int u; } v;
    v.f = f;
    unsigned int r = v.u + 0x7fffu + ((v.u >> 16) & 1u);   // RNE
    return (unsigned short)(r >> 16);
}

// ---------------------------------------------------------------------------
// Shared GEMM mainloop: C[128x128] tile += A[128xK] * B[128xK]^T  (bf16 in,
// fp32 acc). m97 structure: BK=32, global_load_lds width16, 16x16x32 MFMA,
// 4 waves each owning a 64x64 quadrant (4x4 fragments).
// ---------------------------------------------------------------------------
__device__ __forceinline__ void gemm_mainloop(const ushort* __restrict__ Arow,
                                              const ushort* __restrict__ Brow,
                                              int K, ushort* As, ushort* Bs,
                                              floatx4 acc[4][4]) {
    const int t = threadIdx.x;
    const int w = t >> 6;
    const int lane = t & 63;
    const size_t ldb = (size_t)K * 2;  // row pitch in bytes
    const char* gA = (const char*)Arow + (size_t)(t >> 2) * ldb + (size_t)((t & 3) * 16);
    const char* gB = (const char*)Brow + (size_t)(t >> 2) * ldb + (size_t)((t & 3) * 16);
    char* lA = (char*)As + w * 1024;   // wave-uniform LDS base (lane*16 appended by HW)
    char* lB = (char*)Bs + w * 1024;
    const int mw = (w & 1) * 64;
    const int nw = (w >> 1) * 64;
    const int fr = lane & 15;
    const int q8 = (lane >> 4) * 8;
    const int nk = K >> 5;
    for (int kt = 0; kt < nk; ++kt) {
        // stage A tile: 128 rows x 64B; 2 instrs x 256 lanes x 16B
        async16(gA, lA);
        async16(gA + 64 * ldb, lA + 4096);
        async16(gB, lB);
        async16(gB + 64 * ldb, lB + 4096);
        gA += 64;
        gB += 64;
        __syncthreads();  // compiler emits vmcnt(0) drain before barrier
        shortx8 a[4], b[4];
#pragma unroll
        for (int i = 0; i < 4; ++i)
            a[i] = *(const shortx8*)(As + (mw + i * 16 + fr) * 32 + q8);
#pragma unroll
        for (int j = 0; j < 4; ++j)
            b[j] = *(const shortx8*)(Bs + (nw + j * 16 + fr) * 32 + q8);
#pragma unroll
        for (int i = 0; i < 4; ++i)
#pragma unroll
            for (int j = 0; j < 4; ++j)
                acc[i][j] = __builtin_amdgcn_mfma_f32_16x16x32_bf16(a[i], b[j], acc[i][j], 0, 0, 0);
        __syncthreads();
    }
}

// ---------------------------------------------------------------------------
// QKV projection: z=0 -> Q (scaled by 1/32, +bq), z=1 -> K (+bk),
// z=2 -> V stored TRANSPOSED per batch as Vt[b][d][s]  (so PV is a B^T GEMM)
// ---------------------------------------------------------------------------
__global__ __launch_bounds__(256)
void qkv_gemm(const ushort* __restrict__ xb, const ushort* __restrict__ Wb,
              const float* __restrict__ bq, const float* __restrict__ bk,
              const float* __restrict__ bv,
              ushort* __restrict__ Qs, ushort* __restrict__ Ks,
              ushort* __restrict__ Vt) {
    __shared__ __align__(16) ushort lds[8192];
    const int mbase = blockIdx.y * 128;
    const int nbase = blockIdx.x * 128;
    const int z = blockIdx.z;
    floatx4 acc[4][4];
    const floatx4 zero = {0.0f, 0.0f, 0.0f, 0.0f};
#pragma unroll
    for (int i = 0; i < 4; ++i)
#pragma unroll
        for (int j = 0; j < 4; ++j) acc[i][j] = zero;

    gemm_mainloop(xb + (size_t)mbase * 1024,
                  Wb + (size_t)z * (1024 * 1024) + (size_t)nbase * 1024,
                  1024, lds, lds + 4096, acc);

    const int t = threadIdx.x, w = t >> 6, lane = t & 63;
    const int mw = (w & 1) * 64, nw = (w >> 1) * 64;
    const int r0 = mbase + mw + (lane >> 4) * 4;
    const int c0 = nbase + nw + (lane & 15);
    const float* bias = (z == 0) ? bq : (z == 1) ? bk : bv;
    const float scale = (z == 0) ? 0.03125f : 1.0f;  // fold 1/sqrt(1024) into Q
    float bj[4];
#pragma unroll
    for (int j = 0; j < 4; ++j) bj[j] = bias[c0 + j * 16];

    if (z < 2) {
        ushort* O = (z == 0) ? Qs : Ks;
#pragma unroll
        for (int i = 0; i < 4; ++i)
#pragma unroll
            for (int j = 0; j < 4; ++j)
#pragma unroll
                for (int r = 0; r < 4; ++r) {
                    int gr = r0 + i * 16 + r;
                    int gc = c0 + j * 16;
                    O[(size_t)gr * 1024 + gc] = f2bf((acc[i][j][r] + bj[j]) * scale);
                }
    } else {
#pragma unroll
        for (int i = 0; i < 4; ++i)
#pragma unroll
            for (int j = 0; j < 4; ++j)
#pragma unroll
                for (int r = 0; r < 4; ++r) {
                    int gr = r0 + i * 16 + r;           // global row = b*2048 + s
                    int gc = c0 + j * 16;               // d
                    Vt[(size_t)(gr >> 11) * (1024 * 2048) + (size_t)gc * 2048 + (gr & 2047)] =
                        f2bf(acc[i][j][r] + bj[j]);
                }
    }
}

// ---------------------------------------------------------------------------
// Generic batched B^T GEMM, fp32 output. grid.z = batch.
// ---------------------------------------------------------------------------
__global__ __launch_bounds__(256)
void gemm_bt_f32(const ushort* __restrict__ A, size_t sAz,
                 const ushort* __restrict__ B, size_t sBz,
                 float* __restrict__ C, size_t sCz, int N, int K) {
    __shared__ __align__(16) ushort lds[8192];
    const int mbase = blockIdx.y * 128;
    const int nbase = blockIdx.x * 128;
    const int z = blockIdx.z;
    floatx4 acc[4][4];
    const floatx4 zero = {0.0f, 0.0f, 0.0f, 0.0f};
#pragma unroll
    for (int i = 0; i < 4; ++i)
#pragma unroll
        for (int j = 0; j < 4; ++j) acc[i][j] = zero;

    gemm_mainloop(A + z * sAz + (size_t)mbase * K,
                  B + z * sBz + (size_t)nbase * K, K, lds, lds + 4096, acc);

    const int t = threadIdx.x, w = t >> 6, lane = t & 63;
    const int mw = (w & 1) * 64, nw = (w >> 1) * 64;
    const int r0 = mbase + mw + (lane >> 4) * 4;
    const int c0 = nbase + nw + (lane & 15);
    float* Cz = C + z * sCz;
#pragma unroll
    for (int i = 0; i < 4; ++i)
#pragma unroll
        for (int j = 0; j < 4; ++j)
#pragma unroll
            for (int r = 0; r < 4; ++r)
                Cz[(size_t)(r0 + i * 16 + r) * N + (c0 + j * 16)] = acc[i][j][r];
}

// ---------------------------------------------------------------------------
// Row softmax over 2048 keys -> bf16 P. One block (256 thr) per row.
// ---------------------------------------------------------------------------
__global__ __launch_bounds__(256)
void softmax_rows(const float* __restrict__ S, ushort* __restrict__ P) {
    const int row = blockIdx.x;
    const float4* src = (const float4*)(S + (size_t)row * 2048);
    ushortx4* dst = (ushortx4*)(P + (size_t)row * 2048);
    const int t = threadIdx.x;
    const int w = t >> 6, lane = t & 63;
    float4 v0 = src[t];
    float4 v1 = src[t + 256];
    float m = fmaxf(fmaxf(fmaxf(v0.x, v0.y), fmaxf(v0.z, v0.w)),
                    fmaxf(fmaxf(v1.x, v1.y), fmaxf(v1.z, v1.w)));
    for (int o = 32; o > 0; o >>= 1) m = fmaxf(m, __shfl_down(m, o));
    __shared__ float red[4];
    if (lane == 0) red[w] = m;
    __syncthreads();
    m = fmaxf(fmaxf(red[0], red[1]), fmaxf(red[2], red[3]));

    float e0 = __expf(v0.x - m), e1 = __expf(v0.y - m), e2 = __expf(v0.z - m), e3 = __expf(v0.w - m);
    float e4 = __expf(v1.x - m), e5 = __expf(v1.y - m), e6 = __expf(v1.z - m), e7 = __expf(v1.w - m);
    float s = ((e0 + e1) + (e2 + e3)) + ((e4 + e5) + (e6 + e7));
    for (int o = 32; o > 0; o >>= 1) s += __shfl_down(s, o);
    __syncthreads();
    if (lane == 0) red[w] = s;
    __syncthreads();
    float inv = 1.0f / (red[0] + red[1] + red[2] + red[3]);

    ushortx4 o0 = {f2bf(e0 * inv), f2bf(e1 * inv), f2bf(e2 * inv), f2bf(e3 * inv)};
    ushortx4 o1 = {f2bf(e4 * inv), f2bf(e5 * inv), f2bf(e6 * inv), f2bf(e7 * inv)};
    dst[t] = o0;
    dst[t + 256] = o1;
}

// ---------------------------------------------------------------------------
// fp32 -> bf16 cast, 4 elements/thread
// ---------------------------------------------------------------------------
__global__ __launch_bounds__(256)
void cast_bf16(const float* __restrict__ src, ushort* __restrict__ dst, int n4) {
    int i = blockIdx.x * 256 + threadIdx.x;
    if (i >= n4) return;
    float4 v = ((const float4*)src)[i];
    ushortx4 o = {f2bf(v.x), f2bf(v.y), f2bf(v.z), f2bf(v.w)};
    ((ushortx4*)dst)[i] = o;
}

extern "C" void kernel_launch(void* const* d_in, const int* in_sizes, int n_in,
                              void* d_out, int out_size, void* d_ws, size_t ws_size,
                              hipStream_t stream) {
    const float* x  = (const float*)d_in[0];
    const float* Wq = (const float*)d_in[1];
    const float* bq = (const float*)d_in[2];
    const float* Wk = (const float*)d_in[3];
    const float* bk = (const float*)d_in[4];
    const float* Wv = (const float*)d_in[5];
    const float* bv = (const float*)d_in[6];
    float* out = (float*)d_out;

    const size_t R = 8192;   // B*S
    const size_t D = 1024;
    const size_t S = 2048;

    // ws layout (bytes): xb 16.8M | Wb 6.3M | Qs 16.8M | Ks 16.8M | Vt 16.8M |
    //                    Sb 67.1M | Pb 33.6M  = 174,063,616 total
    const size_t need = (R * D + 3 * D * D + 3 * R * D) * 2 + 4 * S * S * 4 + 4 * S * S * 2;
    if (ws_size < need) return;  // leaves poison in d_out -> obvious bench failure

    ushort* xb = (ushort*)d_ws;
    ushort* Wb = xb + R * D;
    ushort* Qs = Wb + 3 * D * D;
    ushort* Ks = Qs + R * D;
    ushort* Vt = Ks + R * D;
    float*  Sb = (float*)(Vt + R * D);
    ushort* Pb = (ushort*)(Sb + (size_t)4 * S * S);

    cast_bf16<<<dim3((unsigned)(R * D / 4 / 256)), dim3(256), 0, stream>>>(x, xb, (int)(R * D / 4));
    cast_bf16<<<dim3((unsigned)(D * D / 4 / 256)), dim3(256), 0, stream>>>(Wq, Wb, (int)(D * D / 4));
    cast_bf16<<<dim3((unsigned)(D * D / 4 / 256)), dim3(256), 0, stream>>>(Wk, Wb + D * D, (int)(D * D / 4));
    cast_bf16<<<dim3((unsigned)(D * D / 4 / 256)), dim3(256), 0, stream>>>(Wv, Wb + 2 * D * D, (int)(D * D / 4));

    // QKV projections: M=8192, N=1024, K=1024, z selects Q/K/V
    qkv_gemm<<<dim3(8, 64, 3), dim3(256), 0, stream>>>(xb, Wb, bq, bk, bv, Qs, Ks, Vt);

    // S = Qs @ K^T per batch: M=N=2048, K=1024 (scale folded into Qs)
    gemm_bt_f32<<<dim3(16, 16, 4), dim3(256), 0, stream>>>(Qs, S * D, Ks, S * D, Sb, S * S,
                                                           (int)S, (int)D);

    // softmax rows -> bf16 P
    softmax_rows<<<dim3((unsigned)(4 * S)), dim3(256), 0, stream>>>(Sb, Pb);

    // O = P @ Vt^T per batch: M=2048, N=1024, K=2048
    gemm_bt_f32<<<dim3(8, 16, 4), dim3(256), 0, stream>>>(Pb, S * S, Vt, D * S, out, S * D,
                                                          (int)D, (int)S);
}

// Round 2
// 281.936 us; speedup vs baseline: 1.1446x; 1.1446x over previous
//
#include <hip/hip_runtime.h>

typedef short shortx8 __attribute__((ext_vector_type(8)));
typedef float floatx4 __attribute__((ext_vector_type(4)));
typedef unsigned short ushortx4 __attribute__((ext_vector_type(4)));
typedef unsigned short ushortx8 __attribute__((ext_vector_type(8)));

typedef __attribute__((address_space(1))) char gchar;
typedef __attribute__((address_space(3))) char lchar;

__device__ __forceinline__ void async16(const void* g, void* l) {
    __builtin_amdgcn_global_load_lds((gchar*)g, (lchar*)l, 16, 0, 0);
}

__device__ __forceinline__ unsigned short f2bf(float f) {
    union { float f; unsigned int u; } v;
    v.f = f;
    unsigned int r = v.u + 0x7fffu + ((v.u >> 16) & 1u);   // RNE
    return (unsigned short)(r >> 16);
}

__device__ __forceinline__ float bf2f(unsigned short h) {
    union { unsigned int u; float f; } v;
    v.u = ((unsigned int)h) << 16;
    return v.f;
}

// ---------------------------------------------------------------------------
// Shared GEMM mainloop: C[128x128] tile += A[128xK] * B[128xK]^T  (bf16 in,
// fp32 acc). m97 structure: BK=32, global_load_lds width16, 16x16x32 MFMA,
// 4 waves each owning a 64x64 quadrant (4x4 fragments).
// ---------------------------------------------------------------------------
__device__ __forceinline__ void gemm_mainloop(const ushort* __restrict__ Arow,
                                              const ushort* __restrict__ Brow,
                                              int K, ushort* As, ushort* Bs,
                                              floatx4 acc[4][4]) {
    const int t = threadIdx.x;
    const int w = t >> 6;
    const int lane = t & 63;
    const size_t ldb = (size_t)K * 2;  // row pitch in bytes
    const char* gA = (const char*)Arow + (size_t)(t >> 2) * ldb + (size_t)((t & 3) * 16);
    const char* gB = (const char*)Brow + (size_t)(t >> 2) * ldb + (size_t)((t & 3) * 16);
    char* lA = (char*)As + w * 1024;   // wave-uniform LDS base (lane*16 appended by HW)
    char* lB = (char*)Bs + w * 1024;
    const int mw = (w & 1) * 64;
    const int nw = (w >> 1) * 64;
    const int fr = lane & 15;
    const int q8 = (lane >> 4) * 8;
    const int nk = K >> 5;
    for (int kt = 0; kt < nk; ++kt) {
        async16(gA, lA);
        async16(gA + 64 * ldb, lA + 4096);
        async16(gB, lB);
        async16(gB + 64 * ldb, lB + 4096);
        gA += 64;
        gB += 64;
        __syncthreads();
        shortx8 a[4], b[4];
#pragma unroll
        for (int i = 0; i < 4; ++i)
            a[i] = *(const shortx8*)(As + (mw + i * 16 + fr) * 32 + q8);
#pragma unroll
        for (int j = 0; j < 4; ++j)
            b[j] = *(const shortx8*)(Bs + (nw + j * 16 + fr) * 32 + q8);
#pragma unroll
        for (int i = 0; i < 4; ++i)
#pragma unroll
            for (int j = 0; j < 4; ++j)
                acc[i][j] = __builtin_amdgcn_mfma_f32_16x16x32_bf16(a[i], b[j], acc[i][j], 0, 0, 0);
        __syncthreads();
    }
}

// ---------------------------------------------------------------------------
// QKV projection: z=0 -> Q (scaled by 1/32, +bq), z=1 -> K (+bk),
// z=2 -> V stored TRANSPOSED per batch as Vt[b][d][s]
// ---------------------------------------------------------------------------
__global__ __launch_bounds__(256, 3)
void qkv_gemm(const ushort* __restrict__ xb, const ushort* __restrict__ Wb,
              const float* __restrict__ bq, const float* __restrict__ bk,
              const float* __restrict__ bv,
              ushort* __restrict__ Qs, ushort* __restrict__ Ks,
              ushort* __restrict__ Vt) {
    __shared__ __align__(16) ushort lds[8192];
    const int mbase = blockIdx.y * 128;
    const int nbase = blockIdx.x * 128;
    const int z = blockIdx.z;
    floatx4 acc[4][4];
    const floatx4 zero = {0.0f, 0.0f, 0.0f, 0.0f};
#pragma unroll
    for (int i = 0; i < 4; ++i)
#pragma unroll
        for (int j = 0; j < 4; ++j) acc[i][j] = zero;

    gemm_mainloop(xb + (size_t)mbase * 1024,
                  Wb + (size_t)z * (1024 * 1024) + (size_t)nbase * 1024,
                  1024, lds, lds + 4096, acc);

    const int t = threadIdx.x, w = t >> 6, lane = t & 63;
    const int mw = (w & 1) * 64, nw = (w >> 1) * 64;
    const int r0 = mbase + mw + (lane >> 4) * 4;
    const int c0 = nbase + nw + (lane & 15);
    const float* bias = (z == 0) ? bq : (z == 1) ? bk : bv;
    const float scale = (z == 0) ? 0.03125f : 1.0f;  // fold 1/sqrt(1024) into Q
    float bj[4];
#pragma unroll
    for (int j = 0; j < 4; ++j) bj[j] = bias[c0 + j * 16];

    if (z < 2) {
        ushort* O = (z == 0) ? Qs : Ks;
#pragma unroll
        for (int i = 0; i < 4; ++i)
#pragma unroll
            for (int j = 0; j < 4; ++j)
#pragma unroll
                for (int r = 0; r < 4; ++r) {
                    int gr = r0 + i * 16 + r;
                    int gc = c0 + j * 16;
                    O[(size_t)gr * 1024 + gc] = f2bf((acc[i][j][r] + bj[j]) * scale);
                }
    } else {
#pragma unroll
        for (int i = 0; i < 4; ++i)
#pragma unroll
            for (int j = 0; j < 4; ++j)
#pragma unroll
                for (int r = 0; r < 4; ++r) {
                    int gr = r0 + i * 16 + r;           // global row = b*2048 + s
                    int gc = c0 + j * 16;               // d
                    Vt[(size_t)(gr >> 11) * (1024 * 2048) + (size_t)gc * 2048 + (gr & 2047)] =
                        f2bf(acc[i][j][r] + bj[j]);
                }
    }
}

// ---------------------------------------------------------------------------
// Batched B^T GEMM, bf16 output (for S = Q K^T). grid.z = batch.
// ---------------------------------------------------------------------------
__global__ __launch_bounds__(256, 3)
void gemm_bt_bf16(const ushort* __restrict__ A, size_t sAz,
                  const ushort* __restrict__ B, size_t sBz,
                  ushort* __restrict__ C, size_t sCz, int N, int K) {
    __shared__ __align__(16) ushort lds[8192];
    const int mbase = blockIdx.y * 128;
    const int nbase = blockIdx.x * 128;
    const int z = blockIdx.z;
    floatx4 acc[4][4];
    const floatx4 zero = {0.0f, 0.0f, 0.0f, 0.0f};
#pragma unroll
    for (int i = 0; i < 4; ++i)
#pragma unroll
        for (int j = 0; j < 4; ++j) acc[i][j] = zero;

    gemm_mainloop(A + z * sAz + (size_t)mbase * K,
                  B + z * sBz + (size_t)nbase * K, K, lds, lds + 4096, acc);

    const int t = threadIdx.x, w = t >> 6, lane = t & 63;
    const int mw = (w & 1) * 64, nw = (w >> 1) * 64;
    const int r0 = mbase + mw + (lane >> 4) * 4;
    const int c0 = nbase + nw + (lane & 15);
    ushort* Cz = C + z * sCz;
#pragma unroll
    for (int i = 0; i < 4; ++i)
#pragma unroll
        for (int j = 0; j < 4; ++j)
#pragma unroll
            for (int r = 0; r < 4; ++r)
                Cz[(size_t)(r0 + i * 16 + r) * N + (c0 + j * 16)] = f2bf(acc[i][j][r]);
}

// ---------------------------------------------------------------------------
// Batched B^T GEMM, fp32 output (for O = P Vt^T). grid.z = batch.
// ---------------------------------------------------------------------------
__global__ __launch_bounds__(256, 3)
void gemm_bt_f32(const ushort* __restrict__ A, size_t sAz,
                 const ushort* __restrict__ B, size_t sBz,
                 float* __restrict__ C, size_t sCz, int N, int K) {
    __shared__ __align__(16) ushort lds[8192];
    const int mbase = blockIdx.y * 128;
    const int nbase = blockIdx.x * 128;
    const int z = blockIdx.z;
    floatx4 acc[4][4];
    const floatx4 zero = {0.0f, 0.0f, 0.0f, 0.0f};
#pragma unroll
    for (int i = 0; i < 4; ++i)
#pragma unroll
        for (int j = 0; j < 4; ++j) acc[i][j] = zero;

    gemm_mainloop(A + z * sAz + (size_t)mbase * K,
                  B + z * sBz + (size_t)nbase * K, K, lds, lds + 4096, acc);

    const int t = threadIdx.x, w = t >> 6, lane = t & 63;
    const int mw = (w & 1) * 64, nw = (w >> 1) * 64;
    const int r0 = mbase + mw + (lane >> 4) * 4;
    const int c0 = nbase + nw + (lane & 15);
    float* Cz = C + z * sCz;
#pragma unroll
    for (int i = 0; i < 4; ++i)
#pragma unroll
        for (int j = 0; j < 4; ++j)
#pragma unroll
            for (int r = 0; r < 4; ++r)
                Cz[(size_t)(r0 + i * 16 + r) * N + (c0 + j * 16)] = acc[i][j][r];
}

// ---------------------------------------------------------------------------
// In-place row softmax over 2048 bf16 logits -> bf16 P. One block per row.
// 256 thr x 8 elems (one b128 load each).
// ---------------------------------------------------------------------------
__global__ __launch_bounds__(256)
void softmax_rows_bf16(ushort* __restrict__ SP) {
    const int row = blockIdx.x;
    ushortx8* base = (ushortx8*)(SP + (size_t)row * 2048);
    const int t = threadIdx.x;
    const int w = t >> 6, lane = t & 63;
    ushortx8 v = base[t];
    float f[8];
#pragma unroll
    for (int k = 0; k < 8; ++k) f[k] = bf2f(v[k]);
    float m = f[0];
#pragma unroll
    for (int k = 1; k < 8; ++k) m = fmaxf(m, f[k]);
    for (int o = 32; o > 0; o >>= 1) m = fmaxf(m, __shfl_down(m, o));
    __shared__ float red[4];
    if (lane == 0) red[w] = m;
    __syncthreads();
    m = fmaxf(fmaxf(red[0], red[1]), fmaxf(red[2], red[3]));

    float e[8], s = 0.0f;
#pragma unroll
    for (int k = 0; k < 8; ++k) { e[k] = __expf(f[k] - m); s += e[k]; }
    for (int o = 32; o > 0; o >>= 1) s += __shfl_down(s, o);
    __syncthreads();           // everyone done reading red (max)
    if (lane == 0) red[w] = s;
    __syncthreads();
    float inv = 1.0f / (red[0] + red[1] + red[2] + red[3]);

    ushortx8 o;
#pragma unroll
    for (int k = 0; k < 8; ++k) o[k] = f2bf(e[k] * inv);
    base[t] = o;
}

// ---------------------------------------------------------------------------
// Merged fp32 -> bf16 cast for x | Wq | Wk | Wv. Destination is one
// contiguous ws region; only the source pointer branches by range.
// ---------------------------------------------------------------------------
__global__ __launch_bounds__(256)
void cast_bf16_all(const float* __restrict__ x, const float* __restrict__ Wq,
                   const float* __restrict__ Wk, const float* __restrict__ Wv,
                   ushort* __restrict__ dst) {
    const int NX = 2097152;   // 8192*1024/4
    const int NW = 262144;    // 1024*1024/4
    int i = blockIdx.x * 256 + threadIdx.x;
    const float* src;
    int off;
    if (i < NX)               { src = x;  off = 0; }
    else if (i < NX + NW)     { src = Wq; off = NX; }
    else if (i < NX + 2 * NW) { src = Wk; off = NX + NW; }
    else                      { src = Wv; off = NX + 2 * NW; }
    float4 v = ((const float4*)src)[i - off];
    ushortx4 o = {f2bf(v.x), f2bf(v.y), f2bf(v.z), f2bf(v.w)};
    ((ushortx4*)dst)[i] = o;
}

extern "C" void kernel_launch(void* const* d_in, const int* in_sizes, int n_in,
                              void* d_out, int out_size, void* d_ws, size_t ws_size,
                              hipStream_t stream) {
    const float* x  = (const float*)d_in[0];
    const float* bq = (const float*)d_in[2];
    const float* bk = (const float*)d_in[4];
    const float* bv = (const float*)d_in[6];
    float* out = (float*)d_out;

    const size_t R = 8192;   // B*S
    const size_t D = 1024;
    const size_t S = 2048;

    // ws layout (elems): xb R*D | Wb 3*D*D | Qs R*D | Ks R*D | Vt R*D | Sb 4*S*S(bf16)
    const size_t need = (4 * R * D + 3 * D * D + 4 * S * S) * 2;
    if (ws_size < need) return;

    ushort* xb = (ushort*)d_ws;
    ushort* Wb = xb + R * D;
    ushort* Qs = Wb + 3 * D * D;
    ushort* Ks = Qs + R * D;
    ushort* Vt = Ks + R * D;
    ushort* Sb = Vt + R * D;   // S scores, then P in place (bf16)

    // casts: (R*D + 3*D*D)/4 float4s / 256 = 11264 blocks
    cast_bf16_all<<<dim3(11264), dim3(256), 0, stream>>>(
        x, (const float*)d_in[1], (const float*)d_in[3], (const float*)d_in[5], xb);

    // QKV projections: M=8192, N=1024, K=1024, z selects Q/K/V
    qkv_gemm<<<dim3(8, 64, 3), dim3(256), 0, stream>>>(xb, Wb, bq, bk, bv, Qs, Ks, Vt);

    // S = Qs @ K^T per batch: M=N=2048, K=1024 (scale folded into Qs), bf16 out
    gemm_bt_bf16<<<dim3(16, 16, 4), dim3(256), 0, stream>>>(Qs, S * D, Ks, S * D, Sb, S * S,
                                                            (int)S, (int)D);

    // softmax rows in place -> bf16 P
    softmax_rows_bf16<<<dim3((unsigned)(4 * S)), dim3(256), 0, stream>>>(Sb);

    // O = P @ Vt^T per batch: M=2048, N=1024, K=2048
    gemm_bt_f32<<<dim3(8, 16, 4), dim3(256), 0, stream>>>(Sb, S * S, Vt, D * S, out, S * D,
                                                          (int)D, (int)S);
}